// Round 4
// baseline (355.365 us; speedup 1.0000x reference)
//
#include <hip/hip_runtime.h>

// ---------------------------------------------------------------------------
// NNSensorResponse: out[s,t] = sum_{b,n} sigmoid(MLPp(x))*MLPa(x)*mask * gauss(t-z)
// B=4,N=8000 (BN=32000), F_IN=3, HID=128, S=1024, T=1024, sigma runtime (=5.0).
// Gaussian band-limited (sigma=5 -> +-31 ticks): 16 buckets of 64-tick
// granularity, each owning a 128-tick span. k_main per (s_tile,bucket,ksplit):
// GEMM1 (hidden @ W2, A-frags gathered DIRECT from global - no LDS, no
// barriers) -> sigmoid*amp -> wave-private LDS transpose -> GEMM2 vs
// precomputed Gaussian tiles (GT). W2 pre-shuffled into MFMA fragment order.
// Sort = single-block ballot counting sort. 5 graph nodes total (was 8).
// ---------------------------------------------------------------------------

#define BN_E   32000
#define HIDW   128
#define S_DIM  1024
#define T_DIM  1024
#define NBKT   16
#define KSPL   8
#define MAXPAD (BN_E + NBKT * 31)        // max padded list length
#define MAXCG  ((MAXPAD + 31) / 32)      // max 32-electron chunks
#define INV_SQRT_2PI 0.3989422804f

typedef __attribute__((ext_vector_type(8))) unsigned short u16x8;
typedef __attribute__((ext_vector_type(8))) __bf16         bf16x8;
typedef __attribute__((ext_vector_type(4))) float          f32x4;

static __device__ __forceinline__ unsigned short f2bf(float f) {
    union { float f; unsigned int u; } v; v.f = f;
    unsigned int r = v.u + 0x7FFFu + ((v.u >> 16) & 1u);   // RNE, inputs finite
    return (unsigned short)(r >> 16);
}

static __device__ __forceinline__ f32x4 mfma16(u16x8 a, u16x8 b, f32x4 c) {
    return __builtin_amdgcn_mfma_f32_16x16x32_bf16(
        __builtin_bit_cast(bf16x8, a), __builtin_bit_cast(bf16x8, b), c, 0, 0, 0);
}

static __device__ __forceinline__ int bucket_of(float z) {
    int b = (int)floorf((z - 31.f) * (1.f / 64.f));
    return min(max(b, 0), NBKT - 1);
}

// ---------------- prep: hidden MLP layers + W2 fragment shuffle ----------------
// blocks [0, 16000): 2 electrons each (hidden layers, bf16 out).
// blocks [16000, 16128): W2 -> MFMA-fragment order, frag[(ks*4+q)*1024+s][j] =
//   bf16(W2[(ks*32+q*8+j)*1024 + s]); coalesced in s.
__global__ __launch_bounds__(256) void k_prep(
    const float* __restrict__ x,
    const float* __restrict__ Wp1, const float* __restrict__ bp1,
    const float* __restrict__ Wa1, const float* __restrict__ ba1,
    const float* __restrict__ Wp2, const float* __restrict__ Wa2,
    unsigned short* __restrict__ HpG, unsigned short* __restrict__ HaG,
    unsigned short* __restrict__ WfP, unsigned short* __restrict__ WfA) {
    int bx = blockIdx.x;
    if (bx < BN_E / 2) {
        int e = bx * 2 + (threadIdx.x >> 7);
        int j = threadIdx.x & 127;
        float x0 = x[e * 3 + 0], x1 = x[e * 3 + 1], x2 = x[e * 3 + 2];
        float hp = x0 * Wp1[j] + x1 * Wp1[HIDW + j] + x2 * Wp1[2 * HIDW + j] + bp1[j];
        float ha = x0 * Wa1[j] + x1 * Wa1[HIDW + j] + x2 * Wa1[2 * HIDW + j] + ba1[j];
        HpG[e * HIDW + j] = f2bf(fmaxf(hp, 0.f));
        HaG[e * HIDW + j] = f2bf(fmaxf(ha, 0.f));
    } else {
        int bid = bx - BN_E / 2;                    // 0..127
        const float* src = (bid & 64) ? Wa2 : Wp2;
        unsigned short* dst = (bid & 64) ? WfA : WfP;
        int rem = bid & 63;
        int kq = rem >> 2;                          // ks*4+q
        int s  = (rem & 3) * 256 + threadIdx.x;
        int ks = kq >> 2, q = kq & 3;
        unsigned short fr[8];
#pragma unroll
        for (int j = 0; j < 8; ++j)
            fr[j] = f2bf(src[(ks * 32 + q * 8 + j) * S_DIM + s]);
        ((u16x8*)dst)[kq * S_DIM + s] = *(u16x8*)fr;
    }
}

// ---------------- sort: single block, ballot counting sort ----------------
// meta[0..15]=cnt, meta[32..47]=padded start (mult 32), meta[48]=padded total.
__global__ __launch_bounds__(1024) void k_sort(const float* __restrict__ z,
                                               int* __restrict__ meta,
                                               int* __restrict__ list) {
    __shared__ int hist[NBKT], cursor[NBKT], pstartL[NBKT], cntL[NBKT];
    int tid = threadIdx.x, lane = tid & 63;
    if (tid < NBKT) hist[tid] = 0;
    __syncthreads();
    for (int e = tid; e < BN_E; e += 1024) {
        int b = bucket_of(z[e]);
#pragma unroll
        for (int bb = 0; bb < NBKT; ++bb) {
            unsigned long long bm = __ballot(b == bb);
            if (bm && lane == (__ffsll((long long)bm) - 1))
                atomicAdd(&hist[bb], __popcll(bm));
        }
    }
    __syncthreads();
    if (tid < NBKT) { cntL[tid] = hist[tid]; meta[tid] = hist[tid]; }
    __syncthreads();
    if (tid == 0) {
        int s = 0;
        for (int i = 0; i < NBKT; ++i) {
            pstartL[i] = s; cursor[i] = s; meta[32 + i] = s;
            s += ((cntL[i] + 31) >> 5) << 5;
        }
        meta[48] = s;
    }
    __syncthreads();
    for (int e = tid; e < BN_E; e += 1024) {
        int b = bucket_of(z[e]);
        int mypos = 0;
#pragma unroll
        for (int bb = 0; bb < NBKT; ++bb) {
            unsigned long long bm = __ballot(b == bb);
            if (bm) {
                int leader = __ffsll((long long)bm) - 1;
                int base = 0;
                if (lane == leader) base = atomicAdd(&cursor[bb], __popcll(bm));
                base = __shfl(base, leader);
                if (b == bb)
                    mypos = base + __popcll(bm & ((1ull << lane) - 1ull));
            }
        }
        list[mypos] = e;
    }
    __syncthreads();
    if (tid < NBKT * 32) {                          // zero pad slots
        int b = tid >> 5, p = tid & 31;
        int cn = cntL[b], pl = ((cn + 31) >> 5) << 5;
        if (cn + p < pl) list[pstartL[b] + cn + p] = 0;
    }
}

// ---------------- Gaussian tiles, sorted+transposed ----------------
// GT[cg*4096 + t_local*32 + e_local] (bf16), coef*mask folded; pads -> 0.
__global__ __launch_bounds__(256) void k_gauss(
    const float* __restrict__ zg, const float* __restrict__ maskg,
    const float* __restrict__ sigp, const int* __restrict__ meta,
    const int* __restrict__ list, unsigned short* __restrict__ GT) {
    int cg = blockIdx.x;
    int pos0 = cg * 32;
    if (pos0 >= meta[48]) return;
    int b = 15;
    while (meta[32 + b] > pos0) --b;          // chunk never crosses a bucket
    int tb = b * 64;
    int cnt = meta[b], pstart = meta[32 + b];
    int t = threadIdx.x, e_l = t & 31, tg = t >> 5;
    int pos = pos0 + e_l;
    bool real = (pos - pstart) < cnt;
    int ev = real ? list[pos] : 0;
    float sigma = sigp[0];
    float coef = INV_SQRT_2PI / sigma;
    float nis2 = -1.f / (2.f * sigma * sigma);
    float zz = real ? zg[ev] : 0.f;
    float cm = real ? coef * maskg[ev] : 0.f;
    unsigned short* dst = GT + cg * 4096;
#pragma unroll
    for (int k = 0; k < 16; ++k) {
        int tl = tg * 16 + k;
        float d = (float)(tb + tl) - zz;
        dst[tl * 32 + e_l] = f2bf(cm * __expf(d * d * nis2));
    }
}

// ---------------- main fused kernel (barrier-free) ----------------
// grid: (8 s_tiles, 16 buckets, KSPL), 256 threads (4 waves).
__global__ __launch_bounds__(256, 2) void k_main(
    const unsigned short* __restrict__ HpG, const unsigned short* __restrict__ HaG,
    const unsigned short* __restrict__ WfP, const unsigned short* __restrict__ WfA,
    const float* __restrict__ bp2, const float* __restrict__ ba2,
    const int* __restrict__ meta, const int* __restrict__ list,
    const unsigned short* __restrict__ GT, float* __restrict__ out) {

    const int s0     = blockIdx.x * 128;
    const int bk     = blockIdx.y;
    const int tb     = bk * 64;                // t span [tb, tb+128)
    const int cnt    = meta[bk];
    const int pstart = meta[32 + bk];          // padded, multiple of 32
    const int nch    = (cnt + 31) >> 5;
    const int per    = (nch + KSPL - 1) / KSPL;
    const int c0     = blockIdx.z * per;
    const int c1     = min(nch, c0 + per);
    if (c0 >= c1) return;

    const int tid = threadIdx.x;
    const int w = tid >> 6, l = tid & 63, q = l >> 4, c = l & 15;

    // only LDS: wave-private Rsp transpose buffer (no __syncthreads anywhere)
    __shared__ __align__(16) unsigned short RspL[128 * 40];

    // W2 fragments, pre-shuffled: 16 coalesced 16B loads per thread.
    const u16x8* WfPv = (const u16x8*)WfP;
    const u16x8* WfAv = (const u16x8*)WfA;
    u16x8 wP[2][4], wA[2][4];
#pragma unroll
    for (int n = 0; n < 2; ++n) {
        int sg = s0 + w * 32 + n * 16 + c;
#pragma unroll
        for (int ks = 0; ks < 4; ++ks) {
            wP[n][ks] = WfPv[(ks * 4 + q) * S_DIM + sg];
            wA[n][ks] = WfAv[(ks * 4 + q) * S_DIM + sg];
        }
    }
    float bp2v[2] = { bp2[s0 + w * 32 + c], bp2[s0 + w * 32 + 16 + c] };
    float ba2v[2] = { ba2[s0 + w * 32 + c], ba2[s0 + w * 32 + 16 + c] };

    const f32x4 z4 = { 0.f, 0.f, 0.f, 0.f };
    f32x4 acc2[2][8];
#pragma unroll
    for (int m = 0; m < 2; ++m)
#pragma unroll
        for (int n8 = 0; n8 < 8; ++n8) acc2[m][n8] = z4;

    const int* lst = list + pstart;
    const unsigned short* gt0 = GT + (size_t)(pstart >> 5) * 4096;

    // software-pipelined list loads (break list -> H dependent chain)
    int ev0 = lst[c0 * 32 + c];
    int ev1 = lst[c0 * 32 + 16 + c];

    for (int ci = c0; ci < c1; ++ci) {
        int nci = min(ci + 1, c1 - 1);
        int ev0n = lst[nci * 32 + c];
        int ev1n = lst[nci * 32 + 16 + c];

        // GT B-fragments early (global, L2-resident; overlap with GEMM1)
        const unsigned short* gt = gt0 + ci * 4096;
        u16x8 bfr[8];
#pragma unroll
        for (int n8 = 0; n8 < 8; ++n8)
            bfr[n8] = *(const u16x8*)&gt[(n8 * 16 + c) * 32 + q * 8];

        // GEMM1: C1[e][s] = H[e][k] @ W2[k][s]; A-frags direct from global
        f32x4 aP[2][2], aA[2][2];
#pragma unroll
        for (int m = 0; m < 2; ++m)
#pragma unroll
            for (int n = 0; n < 2; ++n) { aP[m][n] = z4; aA[m][n] = z4; }
#pragma unroll
        for (int ks = 0; ks < 4; ++ks) {
            u16x8 hp0 = *(const u16x8*)&HpG[ev0 * HIDW + ks * 32 + q * 8];
            u16x8 hp1 = *(const u16x8*)&HpG[ev1 * HIDW + ks * 32 + q * 8];
            u16x8 ha0 = *(const u16x8*)&HaG[ev0 * HIDW + ks * 32 + q * 8];
            u16x8 ha1 = *(const u16x8*)&HaG[ev1 * HIDW + ks * 32 + q * 8];
#pragma unroll
            for (int n = 0; n < 2; ++n) {
                aP[0][n] = mfma16(hp0, wP[n][ks], aP[0][n]);
                aP[1][n] = mfma16(hp1, wP[n][ks], aP[1][n]);
                aA[0][n] = mfma16(ha0, wA[n][ks], aA[0][n]);
                aA[1][n] = mfma16(ha1, wA[n][ks], aA[1][n]);
            }
        }

        // epilogue1: rsp = sigmoid(p+bp2)*(a+ba2); C-layout -> RspL[s][e]
        // rows wave-private; DS ops in-order per wave -> no barrier needed
#pragma unroll
        for (int m = 0; m < 2; ++m)
#pragma unroll
            for (int n = 0; n < 2; ++n) {
                f32x4 p = aP[m][n], a = aA[m][n];
                unsigned long long pk = 0;
#pragma unroll
                for (int r = 0; r < 4; ++r) {
                    float pr = p[r] + bp2v[n];
                    float ar = a[r] + ba2v[n];
                    float sg = __builtin_amdgcn_rcpf(1.f + __expf(-pr));
                    pk |= (unsigned long long)f2bf(sg * ar) << (16 * r);
                }
                int sl = w * 32 + n * 16 + c;        // col of C1 = s
                int e0 = m * 16 + q * 4;             // row of C1 = e
                *(unsigned long long*)&RspL[sl * 40 + e0] = pk;
            }

        // GEMM2: out[s][t] += Rsp[s][e] @ G[e][t]
#pragma unroll
        for (int m = 0; m < 2; ++m) {
            u16x8 afr = *(const u16x8*)&RspL[(w * 32 + m * 16 + c) * 40 + q * 8];
#pragma unroll
            for (int n8 = 0; n8 < 8; ++n8)
                acc2[m][n8] = mfma16(afr, bfr[n8], acc2[m][n8]);
        }

        ev0 = ev0n; ev1 = ev1n;
    }

    // epilogue2: atomic accumulate (bucket spans overlap + ksplit)
#pragma unroll
    for (int m = 0; m < 2; ++m)
#pragma unroll
        for (int n8 = 0; n8 < 8; ++n8) {
            int t = tb + n8 * 16 + c;
            if (t < T_DIM) {
                int srow = s0 + w * 32 + m * 16 + q * 4;
#pragma unroll
                for (int r = 0; r < 4; ++r)
                    atomicAdd(&out[(srow + r) * T_DIM + t], acc2[m][n8][r]);
            }
        }
}

// ---------------- launch ----------------

extern "C" void kernel_launch(void* const* d_in, const int* in_sizes, int n_in,
                              void* d_out, int out_size, void* d_ws, size_t ws_size,
                              hipStream_t stream) {
    const float* x    = (const float*)d_in[0];
    const float* zp   = (const float*)d_in[1];
    const float* mask = (const float*)d_in[2];
    const float* Wp1  = (const float*)d_in[3];
    const float* bp1  = (const float*)d_in[4];
    const float* Wp2  = (const float*)d_in[5];
    const float* bp2  = (const float*)d_in[6];
    const float* Wa1  = (const float*)d_in[7];
    const float* ba1  = (const float*)d_in[8];
    const float* Wa2  = (const float*)d_in[9];
    const float* ba2  = (const float*)d_in[10];
    const float* sig  = (const float*)d_in[11];

    char* ws = (char*)d_ws;
    unsigned short* HpG  = (unsigned short*)(ws);                      //  8,192,000 B
    unsigned short* HaG  = (unsigned short*)(ws + 8192000);            //  8,192,000 B
    unsigned short* WfP  = (unsigned short*)(ws + 16384000);           //    262,144 B
    unsigned short* WfA  = (unsigned short*)(ws + 16646144);           //    262,144 B
    int*            meta = (int*)(ws + 16908288);                      //        256 B
    int*            list = (int*)(ws + 16908544);                      //    130,048 B
    unsigned short* GT   = (unsigned short*)(ws + 17038592);           //  8,323,072 B
    // total ws ~25.4 MB

    hipMemsetAsync(d_out, 0, (size_t)S_DIM * T_DIM * sizeof(float), stream);

    k_prep<<<BN_E / 2 + 128, 256, 0, stream>>>(x, Wp1, bp1, Wa1, ba1, Wp2, Wa2,
                                               HpG, HaG, WfP, WfA);
    k_sort<<<1, 1024, 0, stream>>>(zp, meta, list);
    k_gauss<<<MAXCG, 256, 0, stream>>>(zp, mask, sig, meta, list, GT);

    k_main<<<dim3(8, NBKT, KSPL), 256, 0, stream>>>(
        HpG, HaG, WfP, WfA, bp2, ba2, meta, list, GT, (float*)d_out);
}

// Round 5
// 221.877 us; speedup vs baseline: 1.6016x; 1.6016x over previous
//
#include <hip/hip_runtime.h>

// ---------------------------------------------------------------------------
// NNSensorResponse: out[s,t] = sum_{b,n} sigmoid(MLPp(x))*MLPa(x)*mask * gauss(t-z)
// B=4,N=8000 (BN=32000), F_IN=3, HID=128, S=1024, T=1024, sigma runtime (=5.0).
// Gaussian band-limited (sigma=5 -> +-31 ticks): 16 buckets of 64-tick
// granularity, each owning a 128-tick span. k_main per (s_tile,bucket,ksplit):
// GEMM1 (hidden @ W2, A-frags gathered DIRECT from global - no LDS staging,
// no barriers) -> sigmoid*amp -> wave-private LDS transpose -> GEMM2 vs
// precomputed Gaussian tiles (GT). W2 pre-shuffled into MFMA fragment order.
// R5: revert R4's single-block ballot sort (144 us on 1 CU!) back to the R3
// multi-block counting sort (per-block LDS hist -> 2-phase scan -> scatter).
// ---------------------------------------------------------------------------

#define BN_E   32000
#define NBLK   125          // BN_E / 256
#define HIDW   128
#define S_DIM  1024
#define T_DIM  1024
#define NBKT   16
#define KSPL   8
#define MAXPAD (BN_E + NBKT * 31)        // max padded list length
#define MAXCG  ((MAXPAD + 31) / 32)      // max 32-electron chunks
#define INV_SQRT_2PI 0.3989422804f

typedef __attribute__((ext_vector_type(8))) unsigned short u16x8;
typedef __attribute__((ext_vector_type(8))) __bf16         bf16x8;
typedef __attribute__((ext_vector_type(4))) float          f32x4;

static __device__ __forceinline__ unsigned short f2bf(float f) {
    union { float f; unsigned int u; } v; v.f = f;
    unsigned int r = v.u + 0x7FFFu + ((v.u >> 16) & 1u);   // RNE, inputs finite
    return (unsigned short)(r >> 16);
}

static __device__ __forceinline__ f32x4 mfma16(u16x8 a, u16x8 b, f32x4 c) {
    return __builtin_amdgcn_mfma_f32_16x16x32_bf16(
        __builtin_bit_cast(bf16x8, a), __builtin_bit_cast(bf16x8, b), c, 0, 0, 0);
}

static __device__ __forceinline__ int bucket_of(float z) {
    int b = (int)floorf((z - 31.f) * (1.f / 64.f));
    return min(max(b, 0), NBKT - 1);
}

// ---------------- prep: hidden MLP layers + W2 fragment shuffle ----------------
// blocks [0, 16000): 2 electrons each (hidden layers, bf16 out).
// blocks [16000, 16128): W2 -> MFMA-fragment order, frag[(ks*4+q)*1024+s][j] =
//   bf16(W2[(ks*32+q*8+j)*1024 + s]); coalesced in s.
__global__ __launch_bounds__(256) void k_prep(
    const float* __restrict__ x,
    const float* __restrict__ Wp1, const float* __restrict__ bp1,
    const float* __restrict__ Wa1, const float* __restrict__ ba1,
    const float* __restrict__ Wp2, const float* __restrict__ Wa2,
    unsigned short* __restrict__ HpG, unsigned short* __restrict__ HaG,
    unsigned short* __restrict__ WfP, unsigned short* __restrict__ WfA) {
    int bx = blockIdx.x;
    if (bx < BN_E / 2) {
        int e = bx * 2 + (threadIdx.x >> 7);
        int j = threadIdx.x & 127;
        float x0 = x[e * 3 + 0], x1 = x[e * 3 + 1], x2 = x[e * 3 + 2];
        float hp = x0 * Wp1[j] + x1 * Wp1[HIDW + j] + x2 * Wp1[2 * HIDW + j] + bp1[j];
        float ha = x0 * Wa1[j] + x1 * Wa1[HIDW + j] + x2 * Wa1[2 * HIDW + j] + ba1[j];
        HpG[e * HIDW + j] = f2bf(fmaxf(hp, 0.f));
        HaG[e * HIDW + j] = f2bf(fmaxf(ha, 0.f));
    } else {
        int bid = bx - BN_E / 2;                    // 0..127
        const float* src = (bid & 64) ? Wa2 : Wp2;
        unsigned short* dst = (bid & 64) ? WfA : WfP;
        int rem = bid & 63;
        int kq = rem >> 2;                          // ks*4+q
        int s  = (rem & 3) * 256 + threadIdx.x;
        int ks = kq >> 2, q = kq & 3;
        unsigned short fr[8];
#pragma unroll
        for (int j = 0; j < 8; ++j)
            fr[j] = f2bf(src[(ks * 32 + q * 8 + j) * S_DIM + s]);
        ((u16x8*)dst)[kq * S_DIM + s] = *(u16x8*)fr;
    }
}

// ---------------- sort (R3 scheme): block hist -> scan -> scatter ------------

// per-block LDS histogram -> blockCounts[blk][16]. grid: NBLK x 256.
__global__ __launch_bounds__(256) void k_count_blk(const float* __restrict__ z,
                                                   int* __restrict__ bc) {
    __shared__ int h[NBKT];
    if (threadIdx.x < NBKT) h[threadIdx.x] = 0;
    __syncthreads();
    int e = blockIdx.x * 256 + threadIdx.x;           // BN_E % 256 == 0
    atomicAdd(&h[bucket_of(z[e])], 1);
    __syncthreads();
    if (threadIdx.x < NBKT) bc[blockIdx.x * NBKT + threadIdx.x] = h[threadIdx.x];
}

// meta[0..15]=cnt, meta[32..47]=PADDED start (mult 32), meta[48]=padded total.
// base[blk][b] = intra-bucket offset of block blk. Parallel 2-phase scan.
__global__ __launch_bounds__(256) void k_scan2(const int* __restrict__ bc,
                                               int* meta, int* __restrict__ base) {
    __shared__ int part[16][16];     // [seg][b]
    __shared__ int segoff[16][16];
    int t = threadIdx.x, b = t & 15, seg = t >> 4;    // 16 segs x 8 blocks
    int v[8]; int sum = 0;
#pragma unroll
    for (int i = 0; i < 8; ++i) {
        int blk = seg * 8 + i;
        v[i] = (blk < NBLK) ? bc[blk * NBKT + b] : 0;
        sum += v[i];
    }
    part[seg][b] = sum;
    __syncthreads();
    if (t < NBKT) {                  // t = bucket
        int run = 0;
        for (int s = 0; s < 16; ++s) { segoff[s][t] = run; run += part[s][t]; }
        meta[t] = run;               // cnt
    }
    __syncthreads();
    if (t == 0) {
        int s = 0;
        for (int i = 0; i < NBKT; ++i) {
            meta[32 + i] = s;
            s += ((meta[i] + 31) >> 5) << 5;          // padded bucket length
        }
        meta[48] = s;
    }
    int run = segoff[seg][b];
#pragma unroll
    for (int i = 0; i < 8; ++i) {
        int blk = seg * 8 + i;
        if (blk < NBLK) { base[blk * NBKT + b] = run; run += v[i]; }
    }
}

// deterministic scatter using LDS ranks into padded list. grid: NBLK x 256.
__global__ __launch_bounds__(256) void k_fill_blk(const float* __restrict__ z,
                                                  const int* __restrict__ meta,
                                                  const int* __restrict__ base,
                                                  int* __restrict__ list) {
    __shared__ int h[NBKT];
    if (threadIdx.x < NBKT) h[threadIdx.x] = 0;
    __syncthreads();
    int e = blockIdx.x * 256 + threadIdx.x;
    int b = bucket_of(z[e]);
    int r = atomicAdd(&h[b], 1);
    list[meta[32 + b] + base[blockIdx.x * NBKT + b] + r] = e;
}

// ---------------- Gaussian tiles, sorted+transposed ----------------
// GT[cg*4096 + t_local*32 + e_local] (bf16), coef*mask folded; pads -> 0;
// also zeroes pad slots of list (makes them safe for k_main's H-gather).
__global__ __launch_bounds__(256) void k_gauss(
    const float* __restrict__ zg, const float* __restrict__ maskg,
    const float* __restrict__ sigp, const int* __restrict__ meta,
    int* __restrict__ list, unsigned short* __restrict__ GT) {
    int cg = blockIdx.x;
    int pos0 = cg * 32;
    if (pos0 >= meta[48]) return;
    int b = 15;
    while (meta[32 + b] > pos0) --b;          // chunk never crosses a bucket
    int tb = b * 64;
    int cnt = meta[b], pstart = meta[32 + b];
    int t = threadIdx.x, e_l = t & 31, tg = t >> 5;
    int pos = pos0 + e_l;
    bool real = (pos - pstart) < cnt;
    int ev = real ? list[pos] : 0;
    if (!real && tg == 0) list[pos] = 0;      // zero pad slots
    float sigma = sigp[0];
    float coef = INV_SQRT_2PI / sigma;
    float nis2 = -1.f / (2.f * sigma * sigma);
    float zz = real ? zg[ev] : 0.f;
    float cm = real ? coef * maskg[ev] : 0.f;
    unsigned short* dst = GT + cg * 4096;
#pragma unroll
    for (int k = 0; k < 16; ++k) {
        int tl = tg * 16 + k;
        float d = (float)(tb + tl) - zz;
        dst[tl * 32 + e_l] = f2bf(cm * __expf(d * d * nis2));
    }
}

// ---------------- main fused kernel (barrier-free) ----------------
// grid: (8 s_tiles, 16 buckets, KSPL), 256 threads (4 waves).
__global__ __launch_bounds__(256, 2) void k_main(
    const unsigned short* __restrict__ HpG, const unsigned short* __restrict__ HaG,
    const unsigned short* __restrict__ WfP, const unsigned short* __restrict__ WfA,
    const float* __restrict__ bp2, const float* __restrict__ ba2,
    const int* __restrict__ meta, const int* __restrict__ list,
    const unsigned short* __restrict__ GT, float* __restrict__ out) {

    const int s0     = blockIdx.x * 128;
    const int bk     = blockIdx.y;
    const int tb     = bk * 64;                // t span [tb, tb+128)
    const int cnt    = meta[bk];
    const int pstart = meta[32 + bk];          // padded, multiple of 32
    const int nch    = (cnt + 31) >> 5;
    const int per    = (nch + KSPL - 1) / KSPL;
    const int c0     = blockIdx.z * per;
    const int c1     = min(nch, c0 + per);
    if (c0 >= c1) return;

    const int tid = threadIdx.x;
    const int w = tid >> 6, l = tid & 63, q = l >> 4, c = l & 15;

    // only LDS: wave-private Rsp transpose buffer (no __syncthreads anywhere)
    __shared__ __align__(16) unsigned short RspL[128 * 40];

    // W2 fragments, pre-shuffled: 16 coalesced 16B loads per thread.
    const u16x8* WfPv = (const u16x8*)WfP;
    const u16x8* WfAv = (const u16x8*)WfA;
    u16x8 wP[2][4], wA[2][4];
#pragma unroll
    for (int n = 0; n < 2; ++n) {
        int sg = s0 + w * 32 + n * 16 + c;
#pragma unroll
        for (int ks = 0; ks < 4; ++ks) {
            wP[n][ks] = WfPv[(ks * 4 + q) * S_DIM + sg];
            wA[n][ks] = WfAv[(ks * 4 + q) * S_DIM + sg];
        }
    }
    float bp2v[2] = { bp2[s0 + w * 32 + c], bp2[s0 + w * 32 + 16 + c] };
    float ba2v[2] = { ba2[s0 + w * 32 + c], ba2[s0 + w * 32 + 16 + c] };

    const f32x4 z4 = { 0.f, 0.f, 0.f, 0.f };
    f32x4 acc2[2][8];
#pragma unroll
    for (int m = 0; m < 2; ++m)
#pragma unroll
        for (int n8 = 0; n8 < 8; ++n8) acc2[m][n8] = z4;

    const int* lst = list + pstart;
    const unsigned short* gt0 = GT + (size_t)(pstart >> 5) * 4096;

    // software-pipelined list loads (break list -> H dependent chain)
    int ev0 = lst[c0 * 32 + c];
    int ev1 = lst[c0 * 32 + 16 + c];

    for (int ci = c0; ci < c1; ++ci) {
        int nci = min(ci + 1, c1 - 1);
        int ev0n = lst[nci * 32 + c];
        int ev1n = lst[nci * 32 + 16 + c];

        // GT B-fragments early (global, L2-resident; overlap with GEMM1)
        const unsigned short* gt = gt0 + ci * 4096;
        u16x8 bfr[8];
#pragma unroll
        for (int n8 = 0; n8 < 8; ++n8)
            bfr[n8] = *(const u16x8*)&gt[(n8 * 16 + c) * 32 + q * 8];

        // GEMM1: C1[e][s] = H[e][k] @ W2[k][s]; A-frags direct from global
        f32x4 aP[2][2], aA[2][2];
#pragma unroll
        for (int m = 0; m < 2; ++m)
#pragma unroll
            for (int n = 0; n < 2; ++n) { aP[m][n] = z4; aA[m][n] = z4; }
#pragma unroll
        for (int ks = 0; ks < 4; ++ks) {
            u16x8 hp0 = *(const u16x8*)&HpG[ev0 * HIDW + ks * 32 + q * 8];
            u16x8 hp1 = *(const u16x8*)&HpG[ev1 * HIDW + ks * 32 + q * 8];
            u16x8 ha0 = *(const u16x8*)&HaG[ev0 * HIDW + ks * 32 + q * 8];
            u16x8 ha1 = *(const u16x8*)&HaG[ev1 * HIDW + ks * 32 + q * 8];
#pragma unroll
            for (int n = 0; n < 2; ++n) {
                aP[0][n] = mfma16(hp0, wP[n][ks], aP[0][n]);
                aP[1][n] = mfma16(hp1, wP[n][ks], aP[1][n]);
                aA[0][n] = mfma16(ha0, wA[n][ks], aA[0][n]);
                aA[1][n] = mfma16(ha1, wA[n][ks], aA[1][n]);
            }
        }

        // epilogue1: rsp = sigmoid(p+bp2)*(a+ba2); C-layout -> RspL[s][e]
        // rows wave-private; DS ops in-order per wave -> no barrier needed
#pragma unroll
        for (int m = 0; m < 2; ++m)
#pragma unroll
            for (int n = 0; n < 2; ++n) {
                f32x4 p = aP[m][n], a = aA[m][n];
                unsigned long long pk = 0;
#pragma unroll
                for (int r = 0; r < 4; ++r) {
                    float pr = p[r] + bp2v[n];
                    float ar = a[r] + ba2v[n];
                    float sg = __builtin_amdgcn_rcpf(1.f + __expf(-pr));
                    pk |= (unsigned long long)f2bf(sg * ar) << (16 * r);
                }
                int sl = w * 32 + n * 16 + c;        // col of C1 = s
                int e0 = m * 16 + q * 4;             // row of C1 = e
                *(unsigned long long*)&RspL[sl * 40 + e0] = pk;
            }

        // GEMM2: out[s][t] += Rsp[s][e] @ G[e][t]
#pragma unroll
        for (int m = 0; m < 2; ++m) {
            u16x8 afr = *(const u16x8*)&RspL[(w * 32 + m * 16 + c) * 40 + q * 8];
#pragma unroll
            for (int n8 = 0; n8 < 8; ++n8)
                acc2[m][n8] = mfma16(afr, bfr[n8], acc2[m][n8]);
        }

        ev0 = ev0n; ev1 = ev1n;
    }

    // epilogue2: atomic accumulate (bucket spans overlap + ksplit)
#pragma unroll
    for (int m = 0; m < 2; ++m)
#pragma unroll
        for (int n8 = 0; n8 < 8; ++n8) {
            int t = tb + n8 * 16 + c;
            if (t < T_DIM) {
                int srow = s0 + w * 32 + m * 16 + q * 4;
#pragma unroll
                for (int r = 0; r < 4; ++r)
                    atomicAdd(&out[(srow + r) * T_DIM + t], acc2[m][n8][r]);
            }
        }
}

// ---------------- launch ----------------

extern "C" void kernel_launch(void* const* d_in, const int* in_sizes, int n_in,
                              void* d_out, int out_size, void* d_ws, size_t ws_size,
                              hipStream_t stream) {
    const float* x    = (const float*)d_in[0];
    const float* zp   = (const float*)d_in[1];
    const float* mask = (const float*)d_in[2];
    const float* Wp1  = (const float*)d_in[3];
    const float* bp1  = (const float*)d_in[4];
    const float* Wp2  = (const float*)d_in[5];
    const float* bp2  = (const float*)d_in[6];
    const float* Wa1  = (const float*)d_in[7];
    const float* ba1  = (const float*)d_in[8];
    const float* Wa2  = (const float*)d_in[9];
    const float* ba2  = (const float*)d_in[10];
    const float* sig  = (const float*)d_in[11];

    char* ws = (char*)d_ws;
    unsigned short* HpG  = (unsigned short*)(ws);                      //  8,192,000 B
    unsigned short* HaG  = (unsigned short*)(ws + 8192000);            //  8,192,000 B
    unsigned short* WfP  = (unsigned short*)(ws + 16384000);           //    262,144 B
    unsigned short* WfA  = (unsigned short*)(ws + 16646144);           //    262,144 B
    int*            meta = (int*)(ws + 16908288);                      //        256 B
    int*            list = (int*)(ws + 16908544);                      //    130,048 B
    int*            bc   = (int*)(ws + 17038592);                      //      8,000 B
    int*            base = (int*)(ws + 17046592);                      //      8,000 B
    unsigned short* GT   = (unsigned short*)(ws + 17054592);           //  8,323,072 B
    // total ws ~25.4 MB

    hipMemsetAsync(d_out, 0, (size_t)S_DIM * T_DIM * sizeof(float), stream);

    k_prep<<<BN_E / 2 + 128, 256, 0, stream>>>(x, Wp1, bp1, Wa1, ba1, Wp2, Wa2,
                                               HpG, HaG, WfP, WfA);
    k_count_blk<<<NBLK, 256, 0, stream>>>(zp, bc);
    k_scan2<<<1, 256, 0, stream>>>(bc, meta, base);
    k_fill_blk<<<NBLK, 256, 0, stream>>>(zp, meta, base, list);
    k_gauss<<<MAXCG, 256, 0, stream>>>(zp, mask, sig, meta, list, GT);

    k_main<<<dim3(8, NBKT, KSPL), 256, 0, stream>>>(
        HpG, HaG, WfP, WfA, bp2, ba2, meta, list, GT, (float*)d_out);
}